// Round 6
// baseline (294.116 us; speedup 1.0000x reference)
//
#include <hip/hip_runtime.h>
#include <hip/hip_bf16.h>

typedef __attribute__((ext_vector_type(8))) __bf16 bf16x8;
typedef __attribute__((ext_vector_type(4))) __bf16 bf16x4;
typedef __attribute__((ext_vector_type(4))) float f32x4;
typedef __attribute__((ext_vector_type(16))) float f32x16;

#define D_MODEL 768
#define SEQ     4096
#define NH      12
#define HD      64

// scale * log2(e), folded into Q at projection time
#define QSCALE (0.125f * 1.44269504088896f)

__device__ __forceinline__ void gload_lds16(const void* g, void* l) {
    __builtin_amdgcn_global_load_lds(
        (const __attribute__((address_space(1))) void*)g,
        (__attribute__((address_space(3))) void*)l, 16, 0, 0);
}

// ---------------------------------------------------------------------------
// Kernel 0: fp32 -> bf16 conversion
// ---------------------------------------------------------------------------
__global__ __launch_bounds__(256) void cvt_kernel(
    const float* __restrict__ x,  const float* __restrict__ wq,
    const float* __restrict__ wk, const float* __restrict__ wv,
    const float* __restrict__ wo,
    __bf16* __restrict__ xb,  __bf16* __restrict__ wqb,
    __bf16* __restrict__ wkb, __bf16* __restrict__ wvb,
    __bf16* __restrict__ wob)
{
    const int XV = SEQ * D_MODEL / 4;
    const int WV = D_MODEL * D_MODEL / 4;
    const int total = XV + 4 * WV;
    for (int i = blockIdx.x * blockDim.x + threadIdx.x; i < total;
         i += gridDim.x * blockDim.x) {
        const float* src; __bf16* dst; int j;
        if      (i < XV)          { src = x;  dst = xb;  j = i; }
        else if (i < XV + WV)     { src = wq; dst = wqb; j = i - XV; }
        else if (i < XV + 2*WV)   { src = wk; dst = wkb; j = i - XV - WV; }
        else if (i < XV + 3*WV)   { src = wv; dst = wvb; j = i - XV - 2*WV; }
        else                      { src = wo; dst = wob; j = i - XV - 3*WV; }
        float4 v = ((const float4*)src)[j];
        bf16x4 o;
        o[0] = (__bf16)v.x; o[1] = (__bf16)v.y;
        o[2] = (__bf16)v.z; o[3] = (__bf16)v.w;
        ((bf16x4*)dst)[j] = o;
    }
}

// ---------------------------------------------------------------------------
// Shared 128x128 BT-GEMM core, BK=64, global_load_lds staging, XOR swizzle.
// (identical to R3/R5, which passed)
// ---------------------------------------------------------------------------
__device__ __forceinline__ void gemm128_core(
    const __bf16* __restrict__ A, const __bf16* __restrict__ B, int KD,
    f32x4 acc[4][4], __bf16 (*As)[64], __bf16 (*Bs)[64])
{
    const int t = threadIdx.x;
    const int lane = t & 63, wid = t >> 6;
    const int wm = (wid & 1) * 64, wn = (wid >> 1) * 64;
    const int lr = lane & 15, lc = lane >> 4;
    const int rl = lane >> 3;
    const int cs = (lane & 7) ^ rl;

    const __bf16* ag = A + (size_t)(wid * 32 + rl) * KD + cs * 8;
    const __bf16* bg = B + (size_t)(wid * 32 + rl) * KD + cs * 8;

    for (int kt = 0; kt < KD / 64; ++kt) {
        __syncthreads();
        #pragma unroll
        for (int i = 0; i < 4; ++i) {
            gload_lds16(ag + (size_t)i * 8 * KD + kt * 64,
                        &As[wid * 32 + i * 8][0]);
            gload_lds16(bg + (size_t)i * 8 * KD + kt * 64,
                        &Bs[wid * 32 + i * 8][0]);
        }
        __syncthreads();

        #pragma unroll
        for (int kh = 0; kh < 2; ++kh) {
            bf16x8 af[4], bfr[4];
            #pragma unroll
            for (int mi = 0; mi < 4; ++mi)
                af[mi] = *(const bf16x8*)
                    &As[wm + mi * 16 + lr][(((kh << 2) | lc) ^ (lr & 7)) * 8];
            #pragma unroll
            for (int ni = 0; ni < 4; ++ni)
                bfr[ni] = *(const bf16x8*)
                    &Bs[wn + ni * 16 + lr][(((kh << 2) | lc) ^ (lr & 7)) * 8];
            __builtin_amdgcn_s_setprio(1);
            #pragma unroll
            for (int mi = 0; mi < 4; ++mi)
                #pragma unroll
                for (int ni = 0; ni < 4; ++ni)
                    acc[mi][ni] = __builtin_amdgcn_mfma_f32_16x16x32_bf16(
                        af[mi], bfr[ni], acc[mi][ni], 0, 0, 0);
            __builtin_amdgcn_s_setprio(0);
        }
    }
}

// ---------------------------------------------------------------------------
// Kernel 1: fused QKV projection (unchanged from R5)
// ---------------------------------------------------------------------------
__global__ __launch_bounds__(256) void qkv_gemm(
    const __bf16* __restrict__ xb,
    const __bf16* __restrict__ wqb, const __bf16* __restrict__ wkb,
    const __bf16* __restrict__ wvb,
    const float* __restrict__ bq, const float* __restrict__ bk,
    const float* __restrict__ bv,
    __bf16* __restrict__ Qo, __bf16* __restrict__ Ko,
    __bf16* __restrict__ Vto)
{
    __shared__ __bf16 As[128][64];
    __shared__ __bf16 Bs[128][64];
    const int bm = blockIdx.x;
    const int seg = blockIdx.y / 6, bn = blockIdx.y % 6;
    const __bf16* B  = (seg == 0) ? wqb : (seg == 1) ? wkb : wvb;
    const float* bias = (seg == 0) ? bq : (seg == 1) ? bk : bv;

    f32x4 acc[4][4] = {};
    gemm128_core(xb + (size_t)bm * 128 * D_MODEL,
                 B  + (size_t)bn * 128 * D_MODEL, D_MODEL, acc, As, Bs);

    const int t = threadIdx.x, lane = t & 63, wid = t >> 6;
    const int wm = (wid & 1) * 64, wn = (wid >> 1) * 64;
    const int lr = lane & 15, lc = lane >> 4;
    const int m0 = bm * 128 + wm, n0 = bn * 128 + wn;

    if (seg < 2) {
        __bf16* O = (seg == 0) ? Qo : Ko;
        const float sc = (seg == 0) ? QSCALE : 1.0f;
        #pragma unroll
        for (int mi = 0; mi < 4; ++mi)
            #pragma unroll
            for (int ni = 0; ni < 4; ++ni) {
                int col = n0 + ni * 16 + lr;
                float bb = bias[col];
                #pragma unroll
                for (int r = 0; r < 4; ++r)
                    O[(size_t)(m0 + mi * 16 + lc * 4 + r) * D_MODEL + col] =
                        (__bf16)((acc[mi][ni][r] + bb) * sc);
            }
    } else {
        #pragma unroll
        for (int mi = 0; mi < 4; ++mi)
            #pragma unroll
            for (int ni = 0; ni < 4; ++ni) {
                int col = n0 + ni * 16 + lr;
                float bb = bias[col];
                bf16x4 pk;
                #pragma unroll
                for (int r = 0; r < 4; ++r)
                    pk[r] = (__bf16)(acc[mi][ni][r] + bb);
                *(bf16x4*)&Vto[(size_t)col * SEQ + m0 + mi * 16 + lc * 4] = pk;
            }
    }
}

// ---------------------------------------------------------------------------
// Kernel 2: flash attention, 32x32 MFMA, KV-split across 2 partner waves.
// grid = 1536 blocks (12 heads x 128 q-blocks of 32 rows), 128 threads.
// Wave wid owns kv rows [wid*2048, wid*2048+2048), private online state,
// merged once at the end. K/V read DIRECTLY from global (L2-resident per
// XCD via swizzle) -- no staging, no in-loop barriers.
// ---------------------------------------------------------------------------
__global__ __launch_bounds__(128, 4) void attn_kernel(
    const __bf16* __restrict__ Q, const __bf16* __restrict__ K,
    const __bf16* __restrict__ Vt, __bf16* __restrict__ Attn)
{
    __shared__ __bf16 Ps[2][32][64];    // per-wave P [q][kv], chunk-XOR swizzled
    __shared__ float  Macc[64][32];     // wave-1 acc exchange, chunk-XOR swizzled
    __shared__ float  Mml[2][64];       // wave-1 m, l

    const int bid = blockIdx.x;                  // 1536 = 8 * 192
    const int swz = (bid & 7) * 192 + (bid >> 3);
    const int h  = swz >> 7;                     // 0..11
    const int q0 = (swz & 127) * 32;             // q-block start

    const int t = threadIdx.x, lane = t & 63, wid = t >> 6;
    const int ql = lane & 31;          // q-row / kv-row / d-row within frags
    const int hi = lane >> 5;          // lane-half
    const int sx = lane & 7;           // P chunk-XOR

    // Q fragments (B-operand), pre-scaled by QSCALE at projection
    const __bf16* qrow = Q + (size_t)(q0 + ql) * D_MODEL + h * HD;
    bf16x8 qf[4];
    #pragma unroll
    for (int k4 = 0; k4 < 4; ++k4)
        qf[k4] = *(const bf16x8*)&qrow[k4 * 16 + hi * 8];

    f32x16 acc0 = {}, acc1 = {};   // O^T[d][q=ql]: d 0-31, 32-63
    float m_r = -1e30f, l_r = 0.f;

    const int kt0 = wid * 32;      // this wave's kv-tile range [kt0, kt0+32)

    for (int kk = 0; kk < 32; ++kk) {
        const int kt = kt0 + kk;

        // ---- K frag loads (direct global; rows are 128B-aligned lines) ----
        const __bf16* krow0 = K + (size_t)(kt * 64 + ql) * D_MODEL + h * HD;
        const __bf16* krow1 = krow0 + 32 * D_MODEL;
        bf16x8 kf0[4], kf1[4];
        #pragma unroll
        for (int k4 = 0; k4 < 4; ++k4) {
            kf0[k4] = *(const bf16x8*)&krow0[k4 * 16 + hi * 8];
            kf1[k4] = *(const bf16x8*)&krow1[k4 * 16 + hi * 8];
        }

        // S^T = K Q^T (log2 domain): lane holds S[kv][q=ql],
        // kv = (r&3) + 8*(r>>2) + 4*hi  (+32 for st1)
        f32x16 st0 = {}, st1 = {};
        __builtin_amdgcn_s_setprio(1);
        #pragma unroll
        for (int k4 = 0; k4 < 4; ++k4) {
            st0 = __builtin_amdgcn_mfma_f32_32x32x16_bf16(kf0[k4], qf[k4], st0, 0, 0, 0);
            st1 = __builtin_amdgcn_mfma_f32_32x32x16_bf16(kf1[k4], qf[k4], st1, 0, 0, 0);
        }
        __builtin_amdgcn_s_setprio(0);

        // ---- V frag loads issued early (hide L2 latency under softmax) ----
        const __bf16* vrow0 = Vt + (size_t)(h * HD + ql) * SEQ + kt * 64;
        const __bf16* vrow1 = vrow0 + 32 * SEQ;
        bf16x8 vf0[4], vf1[4];
        #pragma unroll
        for (int kp = 0; kp < 4; ++kp) {
            vf0[kp] = *(const bf16x8*)&vrow0[kp * 16 + hi * 8];
            vf1[kp] = *(const bf16x8*)&vrow1[kp * 16 + hi * 8];
        }

        // ---- online softmax: lane-local + one shfl_xor(32) ----
        float mx = -1e30f;
        #pragma unroll
        for (int r = 0; r < 16; ++r) {
            mx = fmaxf(mx, st0[r]);
            mx = fmaxf(mx, st1[r]);
        }
        mx = fmaxf(mx, __shfl_xor(mx, 32, 64));

        const bool skip = (bool)__all(mx - m_r <= 8.0f);  // defer-max
        float mnew = skip ? m_r : fmaxf(m_r, mx);
        float corr = skip ? 1.0f : exp2f(m_r - mnew);

        float rs = 0.f;
        #pragma unroll
        for (int r = 0; r < 16; ++r) {
            st0[r] = exp2f(st0[r] - mnew);
            st1[r] = exp2f(st1[r] - mnew);
            rs += st0[r] + st1[r];
        }
        rs += __shfl_xor(rs, 32, 64);
        l_r = l_r * corr + rs;
        m_r = mnew;

        if (!skip) {
            #pragma unroll
            for (int r = 0; r < 16; ++r) { acc0[r] *= corr; acc1[r] *= corr; }
        }

        // ---- P -> per-wave LDS, packed b64 swizzled writes ----
        // st reg 4qd+i -> kv = 8qd + 4hi + i  (st1: +32), chunk = kv>>3
        #pragma unroll
        for (int qd = 0; qd < 4; ++qd) {
            union { __bf16 h4[4]; uint2 u; } w0, w1;
            #pragma unroll
            for (int i = 0; i < 4; ++i) {
                w0.h4[i] = (__bf16)st0[4 * qd + i];
                w1.h4[i] = (__bf16)st1[4 * qd + i];
            }
            *(uint2*)&Ps[wid][ql][((qd ^ sx) << 3) + 4 * hi]       = w0.u;
            *(uint2*)&Ps[wid][ql][(((4 + qd) ^ sx) << 3) + 4 * hi] = w1.u;
        }

        // ---- PV: A = Vt rows (d), B = P[kv][q] read from LDS ----
        __builtin_amdgcn_s_setprio(1);
        #pragma unroll
        for (int kp = 0; kp < 4; ++kp) {
            bf16x8 pf = *(const bf16x8*)
                &Ps[wid][ql][((kp * 2 + hi) ^ sx) * 8];
            acc0 = __builtin_amdgcn_mfma_f32_32x32x16_bf16(vf0[kp], pf, acc0, 0, 0, 0);
            acc1 = __builtin_amdgcn_mfma_f32_32x32x16_bf16(vf1[kp], pf, acc1, 0, 0, 0);
        }
        __builtin_amdgcn_s_setprio(0);
    }

    // ---- merge the two kv-half states (same lane <-> same (q,d) elems) ----
    if (wid == 1) {
        #pragma unroll
        for (int j = 0; j < 4; ++j) {
            f32x4 v; v[0] = acc0[4*j]; v[1] = acc0[4*j+1];
            v[2] = acc0[4*j+2]; v[3] = acc0[4*j+3];
            *(f32x4*)&Macc[lane][(j ^ sx) * 4] = v;
        }
        #pragma unroll
        for (int j = 0; j < 4; ++j) {
            f32x4 v; v[0] = acc1[4*j]; v[1] = acc1[4*j+1];
            v[2] = acc1[4*j+2]; v[3] = acc1[4*j+3];
            *(f32x4*)&Macc[lane][((4 + j) ^ sx) * 4] = v;
        }
        Mml[0][lane] = m_r;
        Mml[1][lane] = l_r;
    }
    __syncthreads();
    if (wid == 0) {
        float m1 = Mml[0][lane], l1 = Mml[1][lane];
        float mstar = fmaxf(m_r, m1);
        float s0 = exp2f(m_r - mstar), s1 = exp2f(m1 - mstar);
        float li = 1.0f / (l_r * s0 + l1 * s1);

        __bf16* orow = Attn + (size_t)(q0 + ql) * D_MODEL + h * HD + hi * 4;
        #pragma unroll
        for (int g = 0; g < 4; ++g) {
            f32x4 a1 = *(const f32x4*)&Macc[lane][(g ^ sx) * 4];
            union { __bf16 h4[4]; uint2 v2; } w;
            #pragma unroll
            for (int i = 0; i < 4; ++i)
                w.h4[i] = (__bf16)((acc0[4*g+i] * s0 + a1[i] * s1) * li);
            *(uint2*)&orow[g * 8] = w.v2;

            f32x4 b1 = *(const f32x4*)&Macc[lane][((4 + g) ^ sx) * 4];
            #pragma unroll
            for (int i = 0; i < 4; ++i)
                w.h4[i] = (__bf16)((acc1[4*g+i] * s0 + b1[i] * s1) * li);
            *(uint2*)&orow[32 + g * 8] = w.v2;
        }
    }
}

// ---------------------------------------------------------------------------
// Kernel 3: output projection -> fp32 d_out (unchanged from R5)
// ---------------------------------------------------------------------------
__global__ __launch_bounds__(256) void out_gemm(
    const __bf16* __restrict__ Ab, const __bf16* __restrict__ wob,
    const float* __restrict__ bo, float* __restrict__ out)
{
    __shared__ __bf16 As[128][64];
    __shared__ __bf16 Bs[128][64];
    const int bm = blockIdx.x, bn = blockIdx.y;
    f32x4 acc[4][4] = {};
    gemm128_core(Ab  + (size_t)bm * 128 * D_MODEL,
                 wob + (size_t)bn * 128 * D_MODEL, D_MODEL, acc, As, Bs);

    const int t = threadIdx.x, lane = t & 63, wid = t >> 6;
    const int wm = (wid & 1) * 64, wn = (wid >> 1) * 64;
    const int lr = lane & 15, lc = lane >> 4;
    const int m0 = bm * 128 + wm, n0 = bn * 128 + wn;
    #pragma unroll
    for (int mi = 0; mi < 4; ++mi)
        #pragma unroll
        for (int ni = 0; ni < 4; ++ni) {
            int col = n0 + ni * 16 + lr;
            float bb = bo[col];
            #pragma unroll
            for (int r = 0; r < 4; ++r)
                out[(size_t)(m0 + mi * 16 + lc * 4 + r) * D_MODEL + col] =
                    acc[mi][ni][r] + bb;
        }
}

// ---------------------------------------------------------------------------
extern "C" void kernel_launch(void* const* d_in, const int* in_sizes, int n_in,
                              void* d_out, int out_size, void* d_ws, size_t ws_size,
                              hipStream_t stream) {
    const float* x  = (const float*)d_in[0];
    const float* wq = (const float*)d_in[1];
    const float* bq = (const float*)d_in[2];
    const float* wk = (const float*)d_in[3];
    const float* bk = (const float*)d_in[4];
    const float* wv = (const float*)d_in[5];
    const float* bv = (const float*)d_in[6];
    const float* wo = (const float*)d_in[7];
    const float* bo = (const float*)d_in[8];

    char* ws = (char*)d_ws;
    const size_t XB_SZ = (size_t)SEQ * D_MODEL * 2;
    const size_t W_SZ  = (size_t)D_MODEL * D_MODEL * 2;
    __bf16* xb  = (__bf16*)(ws);
    __bf16* wqb = (__bf16*)(ws + XB_SZ);
    __bf16* wkb = (__bf16*)(ws + XB_SZ + W_SZ);
    __bf16* wvb = (__bf16*)(ws + XB_SZ + 2 * W_SZ);
    __bf16* wob = (__bf16*)(ws + XB_SZ + 3 * W_SZ);
    __bf16* Qb  = (__bf16*)(ws + XB_SZ + 4 * W_SZ);
    __bf16* Kb  = (__bf16*)(ws + 2 * XB_SZ + 4 * W_SZ);
    __bf16* Vtb = (__bf16*)(ws + 3 * XB_SZ + 4 * W_SZ);
    __bf16* Ab  = (__bf16*)(ws + 4 * XB_SZ + 4 * W_SZ);

    cvt_kernel<<<1024, 256, 0, stream>>>(x, wq, wk, wv, wo,
                                         xb, wqb, wkb, wvb, wob);
    qkv_gemm<<<dim3(32, 18), 256, 0, stream>>>(xb, wqb, wkb, wvb,
                                               bq, bk, bv, Qb, Kb, Vtb);
    attn_kernel<<<1536, 128, 0, stream>>>(Qb, Kb, Vtb, Ab);
    out_gemm<<<dim3(32, 6), 256, 0, stream>>>(Ab, wob, bo, (float*)d_out);
}

// Round 7
// 262.641 us; speedup vs baseline: 1.1198x; 1.1198x over previous
//
#include <hip/hip_runtime.h>
#include <hip/hip_bf16.h>

typedef __attribute__((ext_vector_type(8))) __bf16 bf16x8;
typedef __attribute__((ext_vector_type(4))) __bf16 bf16x4;
typedef __attribute__((ext_vector_type(4))) float f32x4;
typedef __attribute__((ext_vector_type(16))) float f32x16;

#define D_MODEL 768
#define SEQ     4096
#define NH      12
#define HD      64

// scale * log2(e), folded into Q at projection time
#define QSCALE (0.125f * 1.44269504088896f)

__device__ __forceinline__ void gload_lds16(const void* g, void* l) {
    __builtin_amdgcn_global_load_lds(
        (const __attribute__((address_space(1))) void*)g,
        (__attribute__((address_space(3))) void*)l, 16, 0, 0);
}

// ---------------------------------------------------------------------------
// Kernel 0: fp32 -> bf16 conversion
// ---------------------------------------------------------------------------
__global__ __launch_bounds__(256) void cvt_kernel(
    const float* __restrict__ x,  const float* __restrict__ wq,
    const float* __restrict__ wk, const float* __restrict__ wv,
    const float* __restrict__ wo,
    __bf16* __restrict__ xb,  __bf16* __restrict__ wqb,
    __bf16* __restrict__ wkb, __bf16* __restrict__ wvb,
    __bf16* __restrict__ wob)
{
    const int XV = SEQ * D_MODEL / 4;
    const int WV = D_MODEL * D_MODEL / 4;
    const int total = XV + 4 * WV;
    for (int i = blockIdx.x * blockDim.x + threadIdx.x; i < total;
         i += gridDim.x * blockDim.x) {
        const float* src; __bf16* dst; int j;
        if      (i < XV)          { src = x;  dst = xb;  j = i; }
        else if (i < XV + WV)     { src = wq; dst = wqb; j = i - XV; }
        else if (i < XV + 2*WV)   { src = wk; dst = wkb; j = i - XV - WV; }
        else if (i < XV + 3*WV)   { src = wv; dst = wvb; j = i - XV - 2*WV; }
        else                      { src = wo; dst = wob; j = i - XV - 3*WV; }
        float4 v = ((const float4*)src)[j];
        bf16x4 o;
        o[0] = (__bf16)v.x; o[1] = (__bf16)v.y;
        o[2] = (__bf16)v.z; o[3] = (__bf16)v.w;
        ((bf16x4*)dst)[j] = o;
    }
}

// ---------------------------------------------------------------------------
// Shared 128x128 BT-GEMM core, BK=64, global_load_lds staging, XOR swizzle.
// ---------------------------------------------------------------------------
__device__ __forceinline__ void gemm128_core(
    const __bf16* __restrict__ A, const __bf16* __restrict__ B, int KD,
    f32x4 acc[4][4], __bf16 (*As)[64], __bf16 (*Bs)[64])
{
    const int t = threadIdx.x;
    const int lane = t & 63, wid = t >> 6;
    const int wm = (wid & 1) * 64, wn = (wid >> 1) * 64;
    const int lr = lane & 15, lc = lane >> 4;
    const int rl = lane >> 3;
    const int cs = (lane & 7) ^ rl;

    const __bf16* ag = A + (size_t)(wid * 32 + rl) * KD + cs * 8;
    const __bf16* bg = B + (size_t)(wid * 32 + rl) * KD + cs * 8;

    for (int kt = 0; kt < KD / 64; ++kt) {
        __syncthreads();
        #pragma unroll
        for (int i = 0; i < 4; ++i) {
            gload_lds16(ag + (size_t)i * 8 * KD + kt * 64,
                        &As[wid * 32 + i * 8][0]);
            gload_lds16(bg + (size_t)i * 8 * KD + kt * 64,
                        &Bs[wid * 32 + i * 8][0]);
        }
        __syncthreads();

        #pragma unroll
        for (int kh = 0; kh < 2; ++kh) {
            bf16x8 af[4], bfr[4];
            #pragma unroll
            for (int mi = 0; mi < 4; ++mi)
                af[mi] = *(const bf16x8*)
                    &As[wm + mi * 16 + lr][(((kh << 2) | lc) ^ (lr & 7)) * 8];
            #pragma unroll
            for (int ni = 0; ni < 4; ++ni)
                bfr[ni] = *(const bf16x8*)
                    &Bs[wn + ni * 16 + lr][(((kh << 2) | lc) ^ (lr & 7)) * 8];
            __builtin_amdgcn_s_setprio(1);
            #pragma unroll
            for (int mi = 0; mi < 4; ++mi)
                #pragma unroll
                for (int ni = 0; ni < 4; ++ni)
                    acc[mi][ni] = __builtin_amdgcn_mfma_f32_16x16x32_bf16(
                        af[mi], bfr[ni], acc[mi][ni], 0, 0, 0);
            __builtin_amdgcn_s_setprio(0);
        }
    }
}

// ---------------------------------------------------------------------------
// Kernel 1: fused QKV projection (unchanged)
// ---------------------------------------------------------------------------
__global__ __launch_bounds__(256) void qkv_gemm(
    const __bf16* __restrict__ xb,
    const __bf16* __restrict__ wqb, const __bf16* __restrict__ wkb,
    const __bf16* __restrict__ wvb,
    const float* __restrict__ bq, const float* __restrict__ bk,
    const float* __restrict__ bv,
    __bf16* __restrict__ Qo, __bf16* __restrict__ Ko,
    __bf16* __restrict__ Vto)
{
    __shared__ __bf16 As[128][64];
    __shared__ __bf16 Bs[128][64];
    const int bm = blockIdx.x;
    const int seg = blockIdx.y / 6, bn = blockIdx.y % 6;
    const __bf16* B  = (seg == 0) ? wqb : (seg == 1) ? wkb : wvb;
    const float* bias = (seg == 0) ? bq : (seg == 1) ? bk : bv;

    f32x4 acc[4][4] = {};
    gemm128_core(xb + (size_t)bm * 128 * D_MODEL,
                 B  + (size_t)bn * 128 * D_MODEL, D_MODEL, acc, As, Bs);

    const int t = threadIdx.x, lane = t & 63, wid = t >> 6;
    const int wm = (wid & 1) * 64, wn = (wid >> 1) * 64;
    const int lr = lane & 15, lc = lane >> 4;
    const int m0 = bm * 128 + wm, n0 = bn * 128 + wn;

    if (seg < 2) {
        __bf16* O = (seg == 0) ? Qo : Ko;
        const float sc = (seg == 0) ? QSCALE : 1.0f;
        #pragma unroll
        for (int mi = 0; mi < 4; ++mi)
            #pragma unroll
            for (int ni = 0; ni < 4; ++ni) {
                int col = n0 + ni * 16 + lr;
                float bb = bias[col];
                #pragma unroll
                for (int r = 0; r < 4; ++r)
                    O[(size_t)(m0 + mi * 16 + lc * 4 + r) * D_MODEL + col] =
                        (__bf16)((acc[mi][ni][r] + bb) * sc);
            }
    } else {
        #pragma unroll
        for (int mi = 0; mi < 4; ++mi)
            #pragma unroll
            for (int ni = 0; ni < 4; ++ni) {
                int col = n0 + ni * 16 + lr;
                float bb = bias[col];
                bf16x4 pk;
                #pragma unroll
                for (int r = 0; r < 4; ++r)
                    pk[r] = (__bf16)(acc[mi][ni][r] + bb);
                *(bf16x4*)&Vto[(size_t)col * SEQ + m0 + mi * 16 + lc * 4] = pk;
            }
    }
}

// ---------------------------------------------------------------------------
// Kernel 2: flash attention, 32x32 MFMA, KV-split across 2 partner waves.
// Same structure as R6 but spill-free: no launch-bounds clamp, K/V
// fragments loaded transiently inside their consuming loops.
// ---------------------------------------------------------------------------
__global__ __launch_bounds__(128) void attn_kernel(
    const __bf16* __restrict__ Q, const __bf16* __restrict__ K,
    const __bf16* __restrict__ Vt, __bf16* __restrict__ Attn)
{
    __shared__ __bf16 Ps[2][32][64];    // per-wave P [q][kv], chunk-XOR swizzled
    __shared__ float  Macc[64][32];     // wave-1 acc exchange, chunk-XOR swizzled
    __shared__ float  Mml[2][64];       // wave-1 m, l

    const int bid = blockIdx.x;                  // 1536 = 8 * 192
    const int swz = (bid & 7) * 192 + (bid >> 3);
    const int h  = swz >> 7;                     // 0..11
    const int q0 = (swz & 127) * 32;             // q-block start

    const int t = threadIdx.x, lane = t & 63, wid = t >> 6;
    const int ql = lane & 31;          // q-row / kv-row / d-row within frags
    const int hi = lane >> 5;          // lane-half
    const int sx = lane & 7;           // P chunk-XOR

    // Q fragments (B-operand), pre-scaled by QSCALE at projection
    const __bf16* qrow = Q + (size_t)(q0 + ql) * D_MODEL + h * HD;
    bf16x8 qf[4];
    #pragma unroll
    for (int k4 = 0; k4 < 4; ++k4)
        qf[k4] = *(const bf16x8*)&qrow[k4 * 16 + hi * 8];

    f32x16 acc0 = {}, acc1 = {};   // O^T[d][q=ql]: d 0-31, 32-63
    float m_r = -1e30f, l_r = 0.f;

    const int kt0 = wid * 32;      // this wave's kv-tile range [kt0, kt0+32)

    for (int kk = 0; kk < 32; ++kk) {
        const int kt = kt0 + kk;

        const __bf16* krow0 = K + (size_t)(kt * 64 + ql) * D_MODEL + h * HD;
        const __bf16* vrow0 = Vt + (size_t)(h * HD + ql) * SEQ + kt * 64;

        // S^T = K Q^T (log2 domain): lane holds S[kv][q=ql],
        // kv = (r&3) + 8*(r>>2) + 4*hi  (+32 for st1)
        // K fragments loaded transiently per k4 (keeps live set small).
        f32x16 st0 = {}, st1 = {};
        #pragma unroll
        for (int k4 = 0; k4 < 4; ++k4) {
            bf16x8 kf0 = *(const bf16x8*)&krow0[k4 * 16 + hi * 8];
            bf16x8 kf1 = *(const bf16x8*)&krow0[32 * D_MODEL + k4 * 16 + hi * 8];
            st0 = __builtin_amdgcn_mfma_f32_32x32x16_bf16(kf0, qf[k4], st0, 0, 0, 0);
            st1 = __builtin_amdgcn_mfma_f32_32x32x16_bf16(kf1, qf[k4], st1, 0, 0, 0);
        }

        // ---- online softmax: lane-local + one shfl_xor(32) ----
        float mx = -1e30f;
        #pragma unroll
        for (int r = 0; r < 16; ++r) {
            mx = fmaxf(mx, st0[r]);
            mx = fmaxf(mx, st1[r]);
        }
        mx = fmaxf(mx, __shfl_xor(mx, 32, 64));

        const bool skip = (bool)__all(mx - m_r <= 8.0f);  // defer-max
        float mnew = skip ? m_r : fmaxf(m_r, mx);
        float corr = skip ? 1.0f : exp2f(m_r - mnew);

        float rs = 0.f;
        #pragma unroll
        for (int r = 0; r < 16; ++r) {
            st0[r] = exp2f(st0[r] - mnew);
            st1[r] = exp2f(st1[r] - mnew);
            rs += st0[r] + st1[r];
        }
        rs += __shfl_xor(rs, 32, 64);
        l_r = l_r * corr + rs;
        m_r = mnew;

        if (!skip) {
            #pragma unroll
            for (int r = 0; r < 16; ++r) { acc0[r] *= corr; acc1[r] *= corr; }
        }

        // ---- P -> per-wave LDS, packed b64 swizzled writes ----
        // st reg 4qd+i -> kv = 8qd + 4hi + i  (st1: +32), chunk = kv>>3
        #pragma unroll
        for (int qd = 0; qd < 4; ++qd) {
            union { __bf16 h4[4]; uint2 u; } w0, w1;
            #pragma unroll
            for (int i = 0; i < 4; ++i) {
                w0.h4[i] = (__bf16)st0[4 * qd + i];
                w1.h4[i] = (__bf16)st1[4 * qd + i];
            }
            *(uint2*)&Ps[wid][ql][((qd ^ sx) << 3) + 4 * hi]       = w0.u;
            *(uint2*)&Ps[wid][ql][(((4 + qd) ^ sx) << 3) + 4 * hi] = w1.u;
        }

        // ---- PV: A = Vt rows (d), B = P[kv][q] from LDS ----
        // V fragments loaded transiently per kp.
        #pragma unroll
        for (int kp = 0; kp < 4; ++kp) {
            bf16x8 pf = *(const bf16x8*)
                &Ps[wid][ql][((kp * 2 + hi) ^ sx) * 8];
            bf16x8 vf0 = *(const bf16x8*)&vrow0[kp * 16 + hi * 8];
            bf16x8 vf1 = *(const bf16x8*)&vrow0[32 * SEQ + kp * 16 + hi * 8];
            acc0 = __builtin_amdgcn_mfma_f32_32x32x16_bf16(vf0, pf, acc0, 0, 0, 0);
            acc1 = __builtin_amdgcn_mfma_f32_32x32x16_bf16(vf1, pf, acc1, 0, 0, 0);
        }
    }

    // ---- merge the two kv-half states (same lane <-> same (q,d) elems) ----
    if (wid == 1) {
        #pragma unroll
        for (int j = 0; j < 4; ++j) {
            f32x4 v; v[0] = acc0[4*j]; v[1] = acc0[4*j+1];
            v[2] = acc0[4*j+2]; v[3] = acc0[4*j+3];
            *(f32x4*)&Macc[lane][(j ^ sx) * 4] = v;
        }
        #pragma unroll
        for (int j = 0; j < 4; ++j) {
            f32x4 v; v[0] = acc1[4*j]; v[1] = acc1[4*j+1];
            v[2] = acc1[4*j+2]; v[3] = acc1[4*j+3];
            *(f32x4*)&Macc[lane][((4 + j) ^ sx) * 4] = v;
        }
        Mml[0][lane] = m_r;
        Mml[1][lane] = l_r;
    }
    __syncthreads();
    if (wid == 0) {
        float m1 = Mml[0][lane], l1 = Mml[1][lane];
        float mstar = fmaxf(m_r, m1);
        float s0 = exp2f(m_r - mstar), s1 = exp2f(m1 - mstar);
        float li = 1.0f / (l_r * s0 + l1 * s1);

        __bf16* orow = Attn + (size_t)(q0 + ql) * D_MODEL + h * HD + hi * 4;
        #pragma unroll
        for (int g = 0; g < 4; ++g) {
            f32x4 a1 = *(const f32x4*)&Macc[lane][(g ^ sx) * 4];
            union { __bf16 h4[4]; uint2 v2; } w;
            #pragma unroll
            for (int i = 0; i < 4; ++i)
                w.h4[i] = (__bf16)((acc0[4*g+i] * s0 + a1[i] * s1) * li);
            *(uint2*)&orow[g * 8] = w.v2;

            f32x4 b1 = *(const f32x4*)&Macc[lane][((4 + g) ^ sx) * 4];
            #pragma unroll
            for (int i = 0; i < 4; ++i)
                w.h4[i] = (__bf16)((acc1[4*g+i] * s0 + b1[i] * s1) * li);
            *(uint2*)&orow[32 + g * 8] = w.v2;
        }
    }
}

// ---------------------------------------------------------------------------
// Kernel 3: output projection -> fp32 d_out (unchanged)
// ---------------------------------------------------------------------------
__global__ __launch_bounds__(256) void out_gemm(
    const __bf16* __restrict__ Ab, const __bf16* __restrict__ wob,
    const float* __restrict__ bo, float* __restrict__ out)
{
    __shared__ __bf16 As[128][64];
    __shared__ __bf16 Bs[128][64];
    const int bm = blockIdx.x, bn = blockIdx.y;
    f32x4 acc[4][4] = {};
    gemm128_core(Ab  + (size_t)bm * 128 * D_MODEL,
                 wob + (size_t)bn * 128 * D_MODEL, D_MODEL, acc, As, Bs);

    const int t = threadIdx.x, lane = t & 63, wid = t >> 6;
    const int wm = (wid & 1) * 64, wn = (wid >> 1) * 64;
    const int lr = lane & 15, lc = lane >> 4;
    const int m0 = bm * 128 + wm, n0 = bn * 128 + wn;
    #pragma unroll
    for (int mi = 0; mi < 4; ++mi)
        #pragma unroll
        for (int ni = 0; ni < 4; ++ni) {
            int col = n0 + ni * 16 + lr;
            float bb = bo[col];
            #pragma unroll
            for (int r = 0; r < 4; ++r)
                out[(size_t)(m0 + mi * 16 + lc * 4 + r) * D_MODEL + col] =
                    acc[mi][ni][r] + bb;
        }
}

// ---------------------------------------------------------------------------
extern "C" void kernel_launch(void* const* d_in, const int* in_sizes, int n_in,
                              void* d_out, int out_size, void* d_ws, size_t ws_size,
                              hipStream_t stream) {
    const float* x  = (const float*)d_in[0];
    const float* wq = (const float*)d_in[1];
    const float* bq = (const float*)d_in[2];
    const float* wk = (const float*)d_in[3];
    const float* bk = (const float*)d_in[4];
    const float* wv = (const float*)d_in[5];
    const float* bv = (const float*)d_in[6];
    const float* wo = (const float*)d_in[7];
    const float* bo = (const float*)d_in[8];

    char* ws = (char*)d_ws;
    const size_t XB_SZ = (size_t)SEQ * D_MODEL * 2;
    const size_t W_SZ  = (size_t)D_MODEL * D_MODEL * 2;
    __bf16* xb  = (__bf16*)(ws);
    __bf16* wqb = (__bf16*)(ws + XB_SZ);
    __bf16* wkb = (__bf16*)(ws + XB_SZ + W_SZ);
    __bf16* wvb = (__bf16*)(ws + XB_SZ + 2 * W_SZ);
    __bf16* wob = (__bf16*)(ws + XB_SZ + 3 * W_SZ);
    __bf16* Qb  = (__bf16*)(ws + XB_SZ + 4 * W_SZ);
    __bf16* Kb  = (__bf16*)(ws + 2 * XB_SZ + 4 * W_SZ);
    __bf16* Vtb = (__bf16*)(ws + 3 * XB_SZ + 4 * W_SZ);
    __bf16* Ab  = (__bf16*)(ws + 4 * XB_SZ + 4 * W_SZ);

    cvt_kernel<<<1024, 256, 0, stream>>>(x, wq, wk, wv, wo,
                                         xb, wqb, wkb, wvb, wob);
    qkv_gemm<<<dim3(32, 18), 256, 0, stream>>>(xb, wqb, wkb, wvb,
                                               bq, bk, bv, Qb, Kb, Vtb);
    attn_kernel<<<1536, 128, 0, stream>>>(Qb, Kb, Vtb, Ab);
    out_gemm<<<dim3(32, 6), 256, 0, stream>>>(Ab, wob, bo, (float*)d_out);
}

// Round 8
// 179.573 us; speedup vs baseline: 1.6379x; 1.4626x over previous
//
#include <hip/hip_runtime.h>
#include <hip/hip_bf16.h>

typedef __attribute__((ext_vector_type(8))) __bf16 bf16x8;
typedef __attribute__((ext_vector_type(4))) __bf16 bf16x4;
typedef __attribute__((ext_vector_type(4))) float f32x4;
typedef __attribute__((ext_vector_type(16))) float f32x16;

#define D_MODEL 768
#define SEQ     4096
#define NH      12
#define HD      64

// scale * log2(e), folded into Q at projection time
#define QSCALE (0.125f * 1.44269504088896f)

__device__ __forceinline__ void gload_lds16(const void* g, void* l) {
    __builtin_amdgcn_global_load_lds(
        (const __attribute__((address_space(1))) void*)g,
        (__attribute__((address_space(3))) void*)l, 16, 0, 0);
}

// ---------------------------------------------------------------------------
// Kernel 0: fp32 -> bf16 conversion
// ---------------------------------------------------------------------------
__global__ __launch_bounds__(256) void cvt_kernel(
    const float* __restrict__ x,  const float* __restrict__ wq,
    const float* __restrict__ wk, const float* __restrict__ wv,
    const float* __restrict__ wo,
    __bf16* __restrict__ xb,  __bf16* __restrict__ wqb,
    __bf16* __restrict__ wkb, __bf16* __restrict__ wvb,
    __bf16* __restrict__ wob)
{
    const int XV = SEQ * D_MODEL / 4;
    const int WV = D_MODEL * D_MODEL / 4;
    const int total = XV + 4 * WV;
    for (int i = blockIdx.x * blockDim.x + threadIdx.x; i < total;
         i += gridDim.x * blockDim.x) {
        const float* src; __bf16* dst; int j;
        if      (i < XV)          { src = x;  dst = xb;  j = i; }
        else if (i < XV + WV)     { src = wq; dst = wqb; j = i - XV; }
        else if (i < XV + 2*WV)   { src = wk; dst = wkb; j = i - XV - WV; }
        else if (i < XV + 3*WV)   { src = wv; dst = wvb; j = i - XV - 2*WV; }
        else                      { src = wo; dst = wob; j = i - XV - 3*WV; }
        float4 v = ((const float4*)src)[j];
        bf16x4 o;
        o[0] = (__bf16)v.x; o[1] = (__bf16)v.y;
        o[2] = (__bf16)v.z; o[3] = (__bf16)v.w;
        ((bf16x4*)dst)[j] = o;
    }
}

// ---------------------------------------------------------------------------
// Shared 128x128 BT-GEMM core, BK=64, global_load_lds staging, XOR swizzle.
// ---------------------------------------------------------------------------
__device__ __forceinline__ void gemm128_core(
    const __bf16* __restrict__ A, const __bf16* __restrict__ B, int KD,
    f32x4 acc[4][4], __bf16 (*As)[64], __bf16 (*Bs)[64])
{
    const int t = threadIdx.x;
    const int lane = t & 63, wid = t >> 6;
    const int wm = (wid & 1) * 64, wn = (wid >> 1) * 64;
    const int lr = lane & 15, lc = lane >> 4;
    const int rl = lane >> 3;
    const int cs = (lane & 7) ^ rl;

    const __bf16* ag = A + (size_t)(wid * 32 + rl) * KD + cs * 8;
    const __bf16* bg = B + (size_t)(wid * 32 + rl) * KD + cs * 8;

    for (int kt = 0; kt < KD / 64; ++kt) {
        __syncthreads();
        #pragma unroll
        for (int i = 0; i < 4; ++i) {
            gload_lds16(ag + (size_t)i * 8 * KD + kt * 64,
                        &As[wid * 32 + i * 8][0]);
            gload_lds16(bg + (size_t)i * 8 * KD + kt * 64,
                        &Bs[wid * 32 + i * 8][0]);
        }
        __syncthreads();

        #pragma unroll
        for (int kh = 0; kh < 2; ++kh) {
            bf16x8 af[4], bfr[4];
            #pragma unroll
            for (int mi = 0; mi < 4; ++mi)
                af[mi] = *(const bf16x8*)
                    &As[wm + mi * 16 + lr][(((kh << 2) | lc) ^ (lr & 7)) * 8];
            #pragma unroll
            for (int ni = 0; ni < 4; ++ni)
                bfr[ni] = *(const bf16x8*)
                    &Bs[wn + ni * 16 + lr][(((kh << 2) | lc) ^ (lr & 7)) * 8];
            __builtin_amdgcn_s_setprio(1);
            #pragma unroll
            for (int mi = 0; mi < 4; ++mi)
                #pragma unroll
                for (int ni = 0; ni < 4; ++ni)
                    acc[mi][ni] = __builtin_amdgcn_mfma_f32_16x16x32_bf16(
                        af[mi], bfr[ni], acc[mi][ni], 0, 0, 0);
            __builtin_amdgcn_s_setprio(0);
        }
    }
}

// ---------------------------------------------------------------------------
// Kernel 1: fused QKV projection (unchanged)
// ---------------------------------------------------------------------------
__global__ __launch_bounds__(256) void qkv_gemm(
    const __bf16* __restrict__ xb,
    const __bf16* __restrict__ wqb, const __bf16* __restrict__ wkb,
    const __bf16* __restrict__ wvb,
    const float* __restrict__ bq, const float* __restrict__ bk,
    const float* __restrict__ bv,
    __bf16* __restrict__ Qo, __bf16* __restrict__ Ko,
    __bf16* __restrict__ Vto)
{
    __shared__ __bf16 As[128][64];
    __shared__ __bf16 Bs[128][64];
    const int bm = blockIdx.x;
    const int seg = blockIdx.y / 6, bn = blockIdx.y % 6;
    const __bf16* B  = (seg == 0) ? wqb : (seg == 1) ? wkb : wvb;
    const float* bias = (seg == 0) ? bq : (seg == 1) ? bk : bv;

    f32x4 acc[4][4] = {};
    gemm128_core(xb + (size_t)bm * 128 * D_MODEL,
                 B  + (size_t)bn * 128 * D_MODEL, D_MODEL, acc, As, Bs);

    const int t = threadIdx.x, lane = t & 63, wid = t >> 6;
    const int wm = (wid & 1) * 64, wn = (wid >> 1) * 64;
    const int lr = lane & 15, lc = lane >> 4;
    const int m0 = bm * 128 + wm, n0 = bn * 128 + wn;

    if (seg < 2) {
        __bf16* O = (seg == 0) ? Qo : Ko;
        const float sc = (seg == 0) ? QSCALE : 1.0f;
        #pragma unroll
        for (int mi = 0; mi < 4; ++mi)
            #pragma unroll
            for (int ni = 0; ni < 4; ++ni) {
                int col = n0 + ni * 16 + lr;
                float bb = bias[col];
                #pragma unroll
                for (int r = 0; r < 4; ++r)
                    O[(size_t)(m0 + mi * 16 + lc * 4 + r) * D_MODEL + col] =
                        (__bf16)((acc[mi][ni][r] + bb) * sc);
            }
    } else {
        #pragma unroll
        for (int mi = 0; mi < 4; ++mi)
            #pragma unroll
            for (int ni = 0; ni < 4; ++ni) {
                int col = n0 + ni * 16 + lr;
                float bb = bias[col];
                bf16x4 pk;
                #pragma unroll
                for (int r = 0; r < 4; ++r)
                    pk[r] = (__bf16)(acc[mi][ni][r] + bb);
                *(bf16x4*)&Vto[(size_t)col * SEQ + m0 + mi * 16 + lc * 4] = pk;
            }
    }
}

// ---------------------------------------------------------------------------
// Kernel 2: flash attention, 32x32 MFMA, 4 waves = 2 q-sub-blocks x 2 KV
// halves. KVBLK=32, K/V staged via global_load_lds into XOR-swizzled LDS,
// double-buffered per half, 1 barrier/tile. End-merge of halves via LDS.
// grid = 768 blocks (12 heads x 64 q-blocks of 64 rows), 256 threads.
// ---------------------------------------------------------------------------
__global__ __launch_bounds__(256) void attn_kernel(
    const __bf16* __restrict__ Q, const __bf16* __restrict__ K,
    const __bf16* __restrict__ Vt, __bf16* __restrict__ Attn)
{
    __shared__ __align__(16) char LDSc[40960];
    __bf16 (*Ks)[32][64] = (__bf16(*)[32][64])(LDSc);           // 4 x 4KB: [half*2+buf]
    __bf16 (*Vs)[64][32] = (__bf16(*)[64][32])(LDSc + 16384);   // 4 x 4KB
    __bf16 (*Ps)[32][32] = (__bf16(*)[32][32])(LDSc + 32768);   // 4 x 2KB per wave
    float* Mg = (float*)LDSc;            // merge acc alias: [qs][64 lanes][32]
    float* Ml = (float*)(LDSc + 32768);  // merge m,l: [qs*2 + {m,l}][64]

    const int bid = blockIdx.x;                 // 768 = 8 * 96
    const int swz = (bid & 7) * 96 + (bid >> 3);
    const int h  = swz >> 6;
    const int q0 = (swz & 63) * 64;

    const int t = threadIdx.x, lane = t & 63, wid = t >> 6;
    const int qs = wid & 1, half = wid >> 1;
    const int ql = lane & 31, hi = lane >> 5;
    const int s7 = ql & 7, s3 = ql & 3;

    // staging source addressing (pre-swizzled global chunks)
    const int krl = lane >> 3, kcs = (lane & 7) ^ (lane >> 3);
    const int vrl = lane >> 2, vcs = (lane & 3) ^ ((lane >> 2) & 3);
    const __bf16* kg = K +
        (size_t)(half * 2048 + qs * 16 + krl) * D_MODEL + h * HD + kcs * 8;
    const __bf16* vg = Vt +
        (size_t)(h * HD + qs * 32 + vrl) * SEQ + half * 2048 + vcs * 8;

    // Q fragments (B-operand): lane (ql,hi) holds Q[q0+qs*32+ql][k4*16+hi*8..]
    const __bf16* qrow = Q + (size_t)(q0 + qs * 32 + ql) * D_MODEL + h * HD;
    bf16x8 qf[4];
    #pragma unroll
    for (int k4 = 0; k4 < 4; ++k4)
        qf[k4] = *(const bf16x8*)&qrow[k4 * 16 + hi * 8];

    f32x16 acc0 = {}, acc1 = {};   // O^T[d][q=ql], d-tiles 0-31 / 32-63
    float m_r = -1e30f, l_r = 0.f;

    // prologue: stage tile 0 of this half into buf 0 (2 K + 2 V per wave)
    {
        gload_lds16(kg,                      &Ks[half * 2][qs * 16][0]);
        gload_lds16(kg + 8 * D_MODEL,        &Ks[half * 2][qs * 16 + 8][0]);
        gload_lds16(vg,                      &Vs[half * 2][qs * 32][0]);
        gload_lds16(vg + (size_t)16 * SEQ,   &Vs[half * 2][qs * 32 + 16][0]);
    }

    const int NT = 2048 / 32;   // 64 tiles per half
    for (int kk = 0; kk < NT; ++kk) {
        const int cur = kk & 1;
        __syncthreads();   // vmcnt(0) drain: tile kk landed; prev reads done

        if (kk + 1 < NT) {
            const int nxt = cur ^ 1;
            const __bf16* kgt = kg + (size_t)(kk + 1) * 32 * D_MODEL;
            const __bf16* vgt = vg + (kk + 1) * 32;
            gload_lds16(kgt,                    &Ks[half * 2 + nxt][qs * 16][0]);
            gload_lds16(kgt + 8 * D_MODEL,      &Ks[half * 2 + nxt][qs * 16 + 8][0]);
            gload_lds16(vgt,                    &Vs[half * 2 + nxt][qs * 32][0]);
            gload_lds16(vgt + (size_t)16 * SEQ, &Vs[half * 2 + nxt][qs * 32 + 16][0]);
        }

        // S^T = K Q^T (log2 domain): lane (ql,hi) holds S[kv][q=ql],
        // kv = (r&3) + 8*(r>>2) + 4*hi
        f32x16 st = {};
        __builtin_amdgcn_s_setprio(1);
        #pragma unroll
        for (int k4 = 0; k4 < 4; ++k4) {
            bf16x8 kf = *(const bf16x8*)
                &Ks[half * 2 + cur][ql][((k4 * 2 + hi) ^ s7) * 8];
            st = __builtin_amdgcn_mfma_f32_32x32x16_bf16(kf, qf[k4], st, 0, 0, 0);
        }
        __builtin_amdgcn_s_setprio(0);

        // ---- online softmax: lane-local + one shfl_xor(32) ----
        float mx = -1e30f;
        #pragma unroll
        for (int r = 0; r < 16; ++r) mx = fmaxf(mx, st[r]);
        mx = fmaxf(mx, __shfl_xor(mx, 32, 64));

        const bool skip = (bool)__all(mx - m_r <= 8.0f);  // defer-max
        float mnew = skip ? m_r : fmaxf(m_r, mx);
        float corr = skip ? 1.0f : exp2f(m_r - mnew);

        float rs = 0.f;
        #pragma unroll
        for (int r = 0; r < 16; ++r) {
            st[r] = exp2f(st[r] - mnew);
            rs += st[r];
        }
        rs += __shfl_xor(rs, 32, 64);
        l_r = l_r * corr + rs;
        m_r = mnew;

        if (!skip) {
            #pragma unroll
            for (int r = 0; r < 16; ++r) { acc0[r] *= corr; acc1[r] *= corr; }
        }

        // ---- P -> per-wave LDS [32 q][32 kv], swizzled b64 writes ----
        // st regs 4g..4g+3 -> kv = 8g + 4hi + i; 16B-chunk g ^ s3, 8B-sub hi
        #pragma unroll
        for (int g = 0; g < 4; ++g) {
            union { __bf16 h4[4]; uint2 u; } w;
            #pragma unroll
            for (int i = 0; i < 4; ++i) w.h4[i] = (__bf16)st[4 * g + i];
            *(uint2*)&Ps[wid][ql][((g ^ s3) << 3) + (hi << 2)] = w.u;
        }

        // ---- PV: A = Vt rows (d), B = P[kv][q=ql]; 2 d-tiles x 2 k-halves ----
        __builtin_amdgcn_s_setprio(1);
        #pragma unroll
        for (int kb = 0; kb < 2; ++kb) {
            bf16x8 pf = *(const bf16x8*)
                &Ps[wid][ql][((kb * 2 + hi) ^ s3) * 8];
            bf16x8 vf0 = *(const bf16x8*)
                &Vs[half * 2 + cur][ql][((kb * 2 + hi) ^ s3) * 8];
            bf16x8 vf1 = *(const bf16x8*)
                &Vs[half * 2 + cur][32 + ql][((kb * 2 + hi) ^ s3) * 8];
            acc0 = __builtin_amdgcn_mfma_f32_32x32x16_bf16(vf0, pf, acc0, 0, 0, 0);
            acc1 = __builtin_amdgcn_mfma_f32_32x32x16_bf16(vf1, pf, acc1, 0, 0, 0);
        }
        __builtin_amdgcn_s_setprio(0);
    }

    // ---- merge the two kv-half states (lane <-> same (q,d) elements) ----
    __syncthreads();
    if (half == 1) {
        float* mybuf = Mg + qs * 2048 + lane * 32;   // 32 floats per lane
        #pragma unroll
        for (int j = 0; j < 4; ++j) {
            f32x4 v; v[0]=acc0[4*j]; v[1]=acc0[4*j+1]; v[2]=acc0[4*j+2]; v[3]=acc0[4*j+3];
            *(f32x4*)&mybuf[(j ^ s7) * 4 + ((lane & 32) ? 0 : 0)] = v;
        }
        #pragma unroll
        for (int j = 0; j < 4; ++j) {
            f32x4 v; v[0]=acc1[4*j]; v[1]=acc1[4*j+1]; v[2]=acc1[4*j+2]; v[3]=acc1[4*j+3];
            *(f32x4*)&mybuf[((4 + j) ^ s7) * 4] = v;
        }
        Ml[(qs * 2 + 0) * 64 + lane] = m_r;
        Ml[(qs * 2 + 1) * 64 + lane] = l_r;
    }
    __syncthreads();
    if (half == 0) {
        float m1 = Ml[(qs * 2 + 0) * 64 + lane];
        float l1 = Ml[(qs * 2 + 1) * 64 + lane];
        float mstar = fmaxf(m_r, m1);
        float s0 = exp2f(m_r - mstar), s1 = exp2f(m1 - mstar);
        float li = 1.0f / (l_r * s0 + l1 * s1);
        const float* obuf = Mg + qs * 2048 + lane * 32;

        __bf16* orow = Attn + (size_t)(q0 + qs * 32 + ql) * D_MODEL
                       + h * HD + hi * 4;
        #pragma unroll
        for (int g = 0; g < 4; ++g) {
            f32x4 a1 = *(const f32x4*)&obuf[(g ^ s7) * 4];
            union { __bf16 h4[4]; uint2 v2; } w;
            #pragma unroll
            for (int i = 0; i < 4; ++i)
                w.h4[i] = (__bf16)((acc0[4*g+i] * s0 + a1[i] * s1) * li);
            *(uint2*)&orow[g * 8] = w.v2;

            f32x4 b1 = *(const f32x4*)&obuf[((4 + g) ^ s7) * 4];
            #pragma unroll
            for (int i = 0; i < 4; ++i)
                w.h4[i] = (__bf16)((acc1[4*g+i] * s0 + b1[i] * s1) * li);
            *(uint2*)&orow[32 + g * 8] = w.v2;
        }
    }
}

// ---------------------------------------------------------------------------
// Kernel 3: output projection -> fp32 d_out (unchanged)
// ---------------------------------------------------------------------------
__global__ __launch_bounds__(256) void out_gemm(
    const __bf16* __restrict__ Ab, const __bf16* __restrict__ wob,
    const float* __restrict__ bo, float* __restrict__ out)
{
    __shared__ __bf16 As[128][64];
    __shared__ __bf16 Bs[128][64];
    const int bm = blockIdx.x, bn = blockIdx.y;
    f32x4 acc[4][4] = {};
    gemm128_core(Ab  + (size_t)bm * 128 * D_MODEL,
                 wob + (size_t)bn * 128 * D_MODEL, D_MODEL, acc, As, Bs);

    const int t = threadIdx.x, lane = t & 63, wid = t >> 6;
    const int wm = (wid & 1) * 64, wn = (wid >> 1) * 64;
    const int lr = lane & 15, lc = lane >> 4;
    const int m0 = bm * 128 + wm, n0 = bn * 128 + wn;
    #pragma unroll
    for (int mi = 0; mi < 4; ++mi)
        #pragma unroll
        for (int ni = 0; ni < 4; ++ni) {
            int col = n0 + ni * 16 + lr;
            float bb = bo[col];
            #pragma unroll
            for (int r = 0; r < 4; ++r)
                out[(size_t)(m0 + mi * 16 + lc * 4 + r) * D_MODEL + col] =
                    acc[mi][ni][r] + bb;
        }
}

// ---------------------------------------------------------------------------
extern "C" void kernel_launch(void* const* d_in, const int* in_sizes, int n_in,
                              void* d_out, int out_size, void* d_ws, size_t ws_size,
                              hipStream_t stream) {
    const float* x  = (const float*)d_in[0];
    const float* wq = (const float*)d_in[1];
    const float* bq = (const float*)d_in[2];
    const float* wk = (const float*)d_in[3];
    const float* bk = (const float*)d_in[4];
    const float* wv = (const float*)d_in[5];
    const float* bv = (const float*)d_in[6];
    const float* wo = (const float*)d_in[7];
    const float* bo = (const float*)d_in[8];

    char* ws = (char*)d_ws;
    const size_t XB_SZ = (size_t)SEQ * D_MODEL * 2;
    const size_t W_SZ  = (size_t)D_MODEL * D_MODEL * 2;
    __bf16* xb  = (__bf16*)(ws);
    __bf16* wqb = (__bf16*)(ws + XB_SZ);
    __bf16* wkb = (__bf16*)(ws + XB_SZ + W_SZ);
    __bf16* wvb = (__bf16*)(ws + XB_SZ + 2 * W_SZ);
    __bf16* wob = (__bf16*)(ws + XB_SZ + 3 * W_SZ);
    __bf16* Qb  = (__bf16*)(ws + XB_SZ + 4 * W_SZ);
    __bf16* Kb  = (__bf16*)(ws + 2 * XB_SZ + 4 * W_SZ);
    __bf16* Vtb = (__bf16*)(ws + 3 * XB_SZ + 4 * W_SZ);
    __bf16* Ab  = (__bf16*)(ws + 4 * XB_SZ + 4 * W_SZ);

    cvt_kernel<<<1024, 256, 0, stream>>>(x, wq, wk, wv, wo,
                                         xb, wqb, wkb, wvb, wob);
    qkv_gemm<<<dim3(32, 18), 256, 0, stream>>>(xb, wqb, wkb, wvb,
                                               bq, bk, bv, Qb, Kb, Vtb);
    attn_kernel<<<768, 256, 0, stream>>>(Qb, Kb, Vtb, Ab);
    out_gemm<<<dim3(32, 6), 256, 0, stream>>>(Ab, wob, bo, (float*)d_out);
}

// Round 9
// 161.862 us; speedup vs baseline: 1.8171x; 1.1094x over previous
//
#include <hip/hip_runtime.h>
#include <hip/hip_bf16.h>

typedef __attribute__((ext_vector_type(8))) __bf16 bf16x8;
typedef __attribute__((ext_vector_type(4))) __bf16 bf16x4;
typedef __attribute__((ext_vector_type(4))) float f32x4;
typedef __attribute__((ext_vector_type(16))) float f32x16;

#define D_MODEL 768
#define SEQ     4096
#define NH      12
#define HD      64

// scale * log2(e), folded into Q at projection time
#define QSCALE (0.125f * 1.44269504088896f)

__device__ __forceinline__ void gload_lds16(const void* g, void* l) {
    __builtin_amdgcn_global_load_lds(
        (const __attribute__((address_space(1))) void*)g,
        (__attribute__((address_space(3))) void*)l, 16, 0, 0);
}

// ---------------------------------------------------------------------------
// Kernel 0: fp32 -> bf16 conversion
// ---------------------------------------------------------------------------
__global__ __launch_bounds__(256) void cvt_kernel(
    const float* __restrict__ x,  const float* __restrict__ wq,
    const float* __restrict__ wk, const float* __restrict__ wv,
    const float* __restrict__ wo,
    __bf16* __restrict__ xb,  __bf16* __restrict__ wqb,
    __bf16* __restrict__ wkb, __bf16* __restrict__ wvb,
    __bf16* __restrict__ wob)
{
    const int XV = SEQ * D_MODEL / 4;
    const int WV = D_MODEL * D_MODEL / 4;
    const int total = XV + 4 * WV;
    for (int i = blockIdx.x * blockDim.x + threadIdx.x; i < total;
         i += gridDim.x * blockDim.x) {
        const float* src; __bf16* dst; int j;
        if      (i < XV)          { src = x;  dst = xb;  j = i; }
        else if (i < XV + WV)     { src = wq; dst = wqb; j = i - XV; }
        else if (i < XV + 2*WV)   { src = wk; dst = wkb; j = i - XV - WV; }
        else if (i < XV + 3*WV)   { src = wv; dst = wvb; j = i - XV - 2*WV; }
        else                      { src = wo; dst = wob; j = i - XV - 3*WV; }
        float4 v = ((const float4*)src)[j];
        bf16x4 o;
        o[0] = (__bf16)v.x; o[1] = (__bf16)v.y;
        o[2] = (__bf16)v.z; o[3] = (__bf16)v.w;
        ((bf16x4*)dst)[j] = o;
    }
}

// ---------------------------------------------------------------------------
// Shared 128x128 BT-GEMM core, BK=64, global_load_lds staging, XOR swizzle.
// ---------------------------------------------------------------------------
__device__ __forceinline__ void gemm128_core(
    const __bf16* __restrict__ A, const __bf16* __restrict__ B, int KD,
    f32x4 acc[4][4], __bf16 (*As)[64], __bf16 (*Bs)[64])
{
    const int t = threadIdx.x;
    const int lane = t & 63, wid = t >> 6;
    const int wm = (wid & 1) * 64, wn = (wid >> 1) * 64;
    const int lr = lane & 15, lc = lane >> 4;
    const int rl = lane >> 3;
    const int cs = (lane & 7) ^ rl;

    const __bf16* ag = A + (size_t)(wid * 32 + rl) * KD + cs * 8;
    const __bf16* bg = B + (size_t)(wid * 32 + rl) * KD + cs * 8;

    for (int kt = 0; kt < KD / 64; ++kt) {
        __syncthreads();
        #pragma unroll
        for (int i = 0; i < 4; ++i) {
            gload_lds16(ag + (size_t)i * 8 * KD + kt * 64,
                        &As[wid * 32 + i * 8][0]);
            gload_lds16(bg + (size_t)i * 8 * KD + kt * 64,
                        &Bs[wid * 32 + i * 8][0]);
        }
        __syncthreads();

        #pragma unroll
        for (int kh = 0; kh < 2; ++kh) {
            bf16x8 af[4], bfr[4];
            #pragma unroll
            for (int mi = 0; mi < 4; ++mi)
                af[mi] = *(const bf16x8*)
                    &As[wm + mi * 16 + lr][(((kh << 2) | lc) ^ (lr & 7)) * 8];
            #pragma unroll
            for (int ni = 0; ni < 4; ++ni)
                bfr[ni] = *(const bf16x8*)
                    &Bs[wn + ni * 16 + lr][(((kh << 2) | lc) ^ (lr & 7)) * 8];
            __builtin_amdgcn_s_setprio(1);
            #pragma unroll
            for (int mi = 0; mi < 4; ++mi)
                #pragma unroll
                for (int ni = 0; ni < 4; ++ni)
                    acc[mi][ni] = __builtin_amdgcn_mfma_f32_16x16x32_bf16(
                        af[mi], bfr[ni], acc[mi][ni], 0, 0, 0);
            __builtin_amdgcn_s_setprio(0);
        }
    }
}

// ---------------------------------------------------------------------------
// Kernel 1: fused QKV projection (unchanged)
// ---------------------------------------------------------------------------
__global__ __launch_bounds__(256) void qkv_gemm(
    const __bf16* __restrict__ xb,
    const __bf16* __restrict__ wqb, const __bf16* __restrict__ wkb,
    const __bf16* __restrict__ wvb,
    const float* __restrict__ bq, const float* __restrict__ bk,
    const float* __restrict__ bv,
    __bf16* __restrict__ Qo, __bf16* __restrict__ Ko,
    __bf16* __restrict__ Vto)
{
    __shared__ __bf16 As[128][64];
    __shared__ __bf16 Bs[128][64];
    const int bm = blockIdx.x;
    const int seg = blockIdx.y / 6, bn = blockIdx.y % 6;
    const __bf16* B  = (seg == 0) ? wqb : (seg == 1) ? wkb : wvb;
    const float* bias = (seg == 0) ? bq : (seg == 1) ? bk : bv;

    f32x4 acc[4][4] = {};
    gemm128_core(xb + (size_t)bm * 128 * D_MODEL,
                 B  + (size_t)bn * 128 * D_MODEL, D_MODEL, acc, As, Bs);

    const int t = threadIdx.x, lane = t & 63, wid = t >> 6;
    const int wm = (wid & 1) * 64, wn = (wid >> 1) * 64;
    const int lr = lane & 15, lc = lane >> 4;
    const int m0 = bm * 128 + wm, n0 = bn * 128 + wn;

    if (seg < 2) {
        __bf16* O = (seg == 0) ? Qo : Ko;
        const float sc = (seg == 0) ? QSCALE : 1.0f;
        #pragma unroll
        for (int mi = 0; mi < 4; ++mi)
            #pragma unroll
            for (int ni = 0; ni < 4; ++ni) {
                int col = n0 + ni * 16 + lr;
                float bb = bias[col];
                #pragma unroll
                for (int r = 0; r < 4; ++r)
                    O[(size_t)(m0 + mi * 16 + lc * 4 + r) * D_MODEL + col] =
                        (__bf16)((acc[mi][ni][r] + bb) * sc);
            }
    } else {
        #pragma unroll
        for (int mi = 0; mi < 4; ++mi)
            #pragma unroll
            for (int ni = 0; ni < 4; ++ni) {
                int col = n0 + ni * 16 + lr;
                float bb = bias[col];
                bf16x4 pk;
                #pragma unroll
                for (int r = 0; r < 4; ++r)
                    pk[r] = (__bf16)(acc[mi][ni][r] + bb);
                *(bf16x4*)&Vto[(size_t)col * SEQ + m0 + mi * 16 + lc * 4] = pk;
            }
    }
}

// ---------------------------------------------------------------------------
// Kernel 2: flash attention, 32x32 MFMA, 4 waves = 2 q-sub-blocks x 2 KV
// halves. KVBLK=32. Conflict-free LDS: K chunk-XOR (row&7), V chunk-XOR
// ((row>>1)&3), P rows padded to 40 elems (no swizzle needed). Manual x2
// unroll so all LDS addresses are loop-invariant per buffer.
// ---------------------------------------------------------------------------
__global__ __launch_bounds__(256) void attn_kernel(
    const __bf16* __restrict__ Q, const __bf16* __restrict__ K,
    const __bf16* __restrict__ Vt, __bf16* __restrict__ Attn)
{
    __shared__ __align__(16) char LDSc[43008];
    __bf16 (*Ks)[32][64] = (__bf16(*)[32][64])(LDSc);           // [half*2+buf]
    __bf16 (*Vs)[64][32] = (__bf16(*)[64][32])(LDSc + 16384);   // [half*2+buf]
    __bf16 (*Ps)[32][40] = (__bf16(*)[32][40])(LDSc + 32768);   // [wid], padded
    float* Mg = (float*)LDSc;            // merge acc (aliases Ks after last use)
    float* Ml = (float*)(LDSc + 16384);  // merge m,l (aliases Vs)

    const int bid = blockIdx.x;                 // 768 = 8 * 96
    const int swz = (bid & 7) * 96 + (bid >> 3);
    const int h  = swz >> 6;
    const int q0 = (swz & 63) * 64;

    const int t = threadIdx.x, lane = t & 63, wid = t >> 6;
    const int qs = wid & 1, half = wid >> 1;
    const int ql = lane & 31, hi = lane >> 5;
    const int s7 = ql & 7;                 // K frag chunk XOR
    const int v2s = (ql >> 1) & 3;         // V frag chunk XOR

    // staging source addressing (inverse-swizzled global chunks)
    const int krl = lane >> 3, kcs = (lane & 7) ^ (lane >> 3);
    const int vrl = lane >> 2, vcs = (lane & 3) ^ ((lane >> 3) & 3);
    const __bf16* kg = K +
        (size_t)(half * 2048 + qs * 16 + krl) * D_MODEL + h * HD + kcs * 8;
    const __bf16* vg = Vt +
        (size_t)(h * HD + qs * 32 + vrl) * SEQ + half * 2048 + vcs * 8;

    // Q fragments (B-operand)
    const __bf16* qrow = Q + (size_t)(q0 + qs * 32 + ql) * D_MODEL + h * HD;
    bf16x8 qf[4];
    #pragma unroll
    for (int k4 = 0; k4 < 4; ++k4)
        qf[k4] = *(const bf16x8*)&qrow[k4 * 16 + hi * 8];

    f32x16 acc0 = {}, acc1 = {};   // O^T[d][q=ql], d-tiles 0-31 / 32-63
    float m_r = -1e30f, l_r = 0.f;

    // prologue: stage tile 0 of this half into buf 0
    gload_lds16(kg,                    &Ks[half * 2][qs * 16][0]);
    gload_lds16(kg + 8 * D_MODEL,      &Ks[half * 2][qs * 16 + 8][0]);
    gload_lds16(vg,                    &Vs[half * 2][qs * 32][0]);
    gload_lds16(vg + (size_t)16 * SEQ, &Vs[half * 2][qs * 32 + 16][0]);

    const int NT = 2048 / 32;   // 64 tiles per half

#define ATILE(CUR, PT, DOPF) do {                                             \
    __syncthreads();                                                          \
    if (DOPF) {                                                               \
        const __bf16* kgt = kg + (size_t)(PT) * 32 * D_MODEL;                 \
        const __bf16* vgt = vg + (PT) * 32;                                   \
        gload_lds16(kgt,               &Ks[half*2 + ((CUR)^1)][qs*16][0]);    \
        gload_lds16(kgt + 8*D_MODEL,   &Ks[half*2 + ((CUR)^1)][qs*16+8][0]);  \
        gload_lds16(vgt,               &Vs[half*2 + ((CUR)^1)][qs*32][0]);    \
        gload_lds16(vgt + (size_t)16*SEQ,                                     \
                    &Vs[half*2 + ((CUR)^1)][qs*32+16][0]);                    \
    }                                                                         \
    f32x16 st = {};                                                           \
    __builtin_amdgcn_s_setprio(1);                                            \
    _Pragma("unroll")                                                         \
    for (int k4 = 0; k4 < 4; ++k4) {                                          \
        bf16x8 kf = *(const bf16x8*)                                          \
            &Ks[half*2 + (CUR)][ql][((k4*2 + hi) ^ s7) * 8];                  \
        st = __builtin_amdgcn_mfma_f32_32x32x16_bf16(kf, qf[k4], st, 0,0,0);  \
    }                                                                         \
    __builtin_amdgcn_s_setprio(0);                                            \
    float mx = -1e30f;                                                        \
    _Pragma("unroll")                                                         \
    for (int r = 0; r < 16; ++r) mx = fmaxf(mx, st[r]);                       \
    mx = fmaxf(mx, __shfl_xor(mx, 32, 64));                                   \
    const bool skip = (bool)__all(mx - m_r <= 8.0f);                          \
    float mnew = skip ? m_r : fmaxf(m_r, mx);                                 \
    float corr = skip ? 1.0f : exp2f(m_r - mnew);                             \
    float rs = 0.f;                                                           \
    _Pragma("unroll")                                                         \
    for (int r = 0; r < 16; ++r) { st[r] = exp2f(st[r] - mnew); rs += st[r]; }\
    rs += __shfl_xor(rs, 32, 64);                                             \
    l_r = l_r * corr + rs;  m_r = mnew;                                       \
    if (!skip) {                                                              \
        _Pragma("unroll")                                                     \
        for (int r = 0; r < 16; ++r) { acc0[r] *= corr; acc1[r] *= corr; }    \
    }                                                                         \
    _Pragma("unroll")                                                         \
    for (int g = 0; g < 4; ++g) {                                             \
        union { __bf16 h4[4]; uint2 u; } w;                                   \
        _Pragma("unroll")                                                     \
        for (int i = 0; i < 4; ++i) w.h4[i] = (__bf16)st[4*g + i];            \
        *(uint2*)&Ps[wid][ql][g * 8 + hi * 4] = w.u;                          \
    }                                                                         \
    __builtin_amdgcn_s_setprio(1);                                            \
    _Pragma("unroll")                                                         \
    for (int kb = 0; kb < 2; ++kb) {                                          \
        bf16x8 pf = *(const bf16x8*)&Ps[wid][ql][(kb*2 + hi) * 8];            \
        bf16x8 vf0 = *(const bf16x8*)                                         \
            &Vs[half*2 + (CUR)][ql][((kb*2 + hi) ^ v2s) * 8];                 \
        bf16x8 vf1 = *(const bf16x8*)                                         \
            &Vs[half*2 + (CUR)][32 + ql][((kb*2 + hi) ^ v2s) * 8];            \
        acc0 = __builtin_amdgcn_mfma_f32_32x32x16_bf16(vf0, pf, acc0, 0,0,0); \
        acc1 = __builtin_amdgcn_mfma_f32_32x32x16_bf16(vf1, pf, acc1, 0,0,0); \
    }                                                                         \
    __builtin_amdgcn_s_setprio(0);                                            \
} while (0)

    for (int kk = 0; kk < NT; kk += 2) {
        ATILE(0, kk + 1, 1);
        ATILE(1, kk + 2, (kk + 2 < NT));
    }
#undef ATILE

    // ---- merge the two kv-half states (lane <-> same (q,d) elements) ----
    __syncthreads();
    if (half == 1) {
        float* mybuf = Mg + qs * 2048 + lane * 32;   // 32 floats per lane
        #pragma unroll
        for (int j = 0; j < 4; ++j) {
            f32x4 v; v[0]=acc0[4*j]; v[1]=acc0[4*j+1]; v[2]=acc0[4*j+2]; v[3]=acc0[4*j+3];
            *(f32x4*)&mybuf[(j ^ s7) * 4] = v;
        }
        #pragma unroll
        for (int j = 0; j < 4; ++j) {
            f32x4 v; v[0]=acc1[4*j]; v[1]=acc1[4*j+1]; v[2]=acc1[4*j+2]; v[3]=acc1[4*j+3];
            *(f32x4*)&mybuf[((4 + j) ^ s7) * 4] = v;
        }
        Ml[(qs * 2 + 0) * 64 + lane] = m_r;
        Ml[(qs * 2 + 1) * 64 + lane] = l_r;
    }
    __syncthreads();
    if (half == 0) {
        float m1 = Ml[(qs * 2 + 0) * 64 + lane];
        float l1 = Ml[(qs * 2 + 1) * 64 + lane];
        float mstar = fmaxf(m_r, m1);
        float s0 = exp2f(m_r - mstar), s1 = exp2f(m1 - mstar);
        float li = 1.0f / (l_r * s0 + l1 * s1);
        const float* obuf = Mg + qs * 2048 + lane * 32;

        __bf16* orow = Attn + (size_t)(q0 + qs * 32 + ql) * D_MODEL
                       + h * HD + hi * 4;
        #pragma unroll
        for (int g = 0; g < 4; ++g) {
            f32x4 a1 = *(const f32x4*)&obuf[(g ^ s7) * 4];
            union { __bf16 h4[4]; uint2 v2; } w;
            #pragma unroll
            for (int i = 0; i < 4; ++i)
                w.h4[i] = (__bf16)((acc0[4*g+i] * s0 + a1[i] * s1) * li);
            *(uint2*)&orow[g * 8] = w.v2;

            f32x4 b1 = *(const f32x4*)&obuf[((4 + g) ^ s7) * 4];
            #pragma unroll
            for (int i = 0; i < 4; ++i)
                w.h4[i] = (__bf16)((acc1[4*g+i] * s0 + b1[i] * s1) * li);
            *(uint2*)&orow[32 + g * 8] = w.v2;
        }
    }
}

// ---------------------------------------------------------------------------
// Kernel 3: output projection -> fp32 d_out (unchanged)
// ---------------------------------------------------------------------------
__global__ __launch_bounds__(256) void out_gemm(
    const __bf16* __restrict__ Ab, const __bf16* __restrict__ wob,
    const float* __restrict__ bo, float* __restrict__ out)
{
    __shared__ __bf16 As[128][64];
    __shared__ __bf16 Bs[128][64];
    const int bm = blockIdx.x, bn = blockIdx.y;
    f32x4 acc[4][4] = {};
    gemm128_core(Ab  + (size_t)bm * 128 * D_MODEL,
                 wob + (size_t)bn * 128 * D_MODEL, D_MODEL, acc, As, Bs);

    const int t = threadIdx.x, lane = t & 63, wid = t >> 6;
    const int wm = (wid & 1) * 64, wn = (wid >> 1) * 64;
    const int lr = lane & 15, lc = lane >> 4;
    const int m0 = bm * 128 + wm, n0 = bn * 128 + wn;
    #pragma unroll
    for (int mi = 0; mi < 4; ++mi)
        #pragma unroll
        for (int ni = 0; ni < 4; ++ni) {
            int col = n0 + ni * 16 + lr;
            float bb = bo[col];
            #pragma unroll
            for (int r = 0; r < 4; ++r)
                out[(size_t)(m0 + mi * 16 + lc * 4 + r) * D_MODEL + col] =
                    acc[mi][ni][r] + bb;
        }
}

// ---------------------------------------------------------------------------
extern "C" void kernel_launch(void* const* d_in, const int* in_sizes, int n_in,
                              void* d_out, int out_size, void* d_ws, size_t ws_size,
                              hipStream_t stream) {
    const float* x  = (const float*)d_in[0];
    const float* wq = (const float*)d_in[1];
    const float* bq = (const float*)d_in[2];
    const float* wk = (const float*)d_in[3];
    const float* bk = (const float*)d_in[4];
    const float* wv = (const float*)d_in[5];
    const float* bv = (const float*)d_in[6];
    const float* wo = (const float*)d_in[7];
    const float* bo = (const float*)d_in[8];

    char* ws = (char*)d_ws;
    const size_t XB_SZ = (size_t)SEQ * D_MODEL * 2;
    const size_t W_SZ  = (size_t)D_MODEL * D_MODEL * 2;
    __bf16* xb  = (__bf16*)(ws);
    __bf16* wqb = (__bf16*)(ws + XB_SZ);
    __bf16* wkb = (__bf16*)(ws + XB_SZ + W_SZ);
    __bf16* wvb = (__bf16*)(ws + XB_SZ + 2 * W_SZ);
    __bf16* wob = (__bf16*)(ws + XB_SZ + 3 * W_SZ);
    __bf16* Qb  = (__bf16*)(ws + XB_SZ + 4 * W_SZ);
    __bf16* Kb  = (__bf16*)(ws + 2 * XB_SZ + 4 * W_SZ);
    __bf16* Vtb = (__bf16*)(ws + 3 * XB_SZ + 4 * W_SZ);
    __bf16* Ab  = (__bf16*)(ws + 4 * XB_SZ + 4 * W_SZ);

    cvt_kernel<<<1024, 256, 0, stream>>>(x, wq, wk, wv, wo,
                                         xb, wqb, wkb, wvb, wob);
    qkv_gemm<<<dim3(32, 18), 256, 0, stream>>>(xb, wqb, wkb, wvb,
                                               bq, bk, bv, Qb, Kb, Vtb);
    attn_kernel<<<768, 256, 0, stream>>>(Qb, Kb, Vtb, Ab);
    out_gemm<<<dim3(32, 6), 256, 0, stream>>>(Ab, wob, bo, (float*)d_out);
}